// Round 12
// baseline (82.150 us; speedup 1.0000x reference)
//
#include <hip/hip_runtime.h>
#include <hip/hip_bf16.h>
#include <math.h>

#define NSP 4096   // H*W
#define CC  128    // channels
#define CIC 64     // inter channels
#define NB  4      // batch
#define LOG2E 1.4426950408889634f

typedef unsigned short u16;
typedef unsigned int u32;
typedef short s8bf __attribute__((ext_vector_type(8)));
typedef float f32x4 __attribute__((ext_vector_type(4)));
typedef float f32x2 __attribute__((ext_vector_type(2)));
typedef float f32x16 __attribute__((ext_vector_type(16)));

#define MFMA32(a, b, c) __builtin_amdgcn_mfma_f32_32x32x16_bf16(a, b, c, 0, 0, 0)

// workspace byte offsets
#define WSB_PB    0                              // bf16 [B][64][NSP] g channel-major
#define WSB_TH    (NB * CIC * NSP * 2)           // bf16 [B][NSP][64] theta*log2e token-major
#define WSB_PH    (WSB_TH + NB * NSP * CIC * 2)  // bf16 [B][NSP][64] phi token-major
#define WSB_OP    (WSB_PH + NB * NSP * CIC * 2)  // f32 [B][2][NSP][64] O partials (8MB)
#define WSB_LP    (WSB_OP + (size_t)NB * 2 * NSP * CIC * 4)  // f32 [B][2][NSP]
#define WSB_WT4   (WSB_LP + NB * 2 * NSP * 4)    // f32 [128][64][4] proj weights
#define WSB_WT2P  (WSB_WT4 + CC * 256 * 4)       // f32 [64][64][2] wconv weight pairs
#define WSB_PARTS (WSB_WT2P + CIC * CC * 4)      // f32 [2][128] (sum, sumsq)

__device__ __forceinline__ u16 f2bf(float f) {
    union { float f; unsigned u; } v; v.f = f;
    unsigned r = v.u + 0x7fffu + ((v.u >> 16) & 1u);
    return (u16)(r >> 16);
}

// -------------------- Kernel 0: weight repack prep + parts zero -----------------
__global__ __launch_bounds__(256) void prep_kernel(
    const float* __restrict__ g_w, const float* __restrict__ t_w,
    const float* __restrict__ p_w, const float* __restrict__ w_w,
    float* __restrict__ wT4, float* __restrict__ wT2p,
    float* __restrict__ parts)
{
    const int c = blockIdx.x;
    const int o = threadIdx.x;
    if (c == 0) parts[o] = 0.f;          // zero [2][128] stats accumulators
    if (o < 192) {
        float v;
        if (o < 64)       v = g_w[o * CC + c];
        else if (o < 128) v = t_w[(o - 64) * CC + c] * LOG2E;
        else              v = p_w[(o - 128) * CC + c];
        wT4[(c << 8) + ((o & 63) << 2) + (o >> 6)] = v;
    } else {
        wT4[(c << 8) + ((o - 192) << 2) + 3] = 0.f;
    }
    if (o < CIC)
        wT2p[(o << 7) + ((c & 63) << 1) + (c >> 6)] = w_w[c * CIC + o];
}

// -------------------- Kernel 1: fused 1x1 projections ---------------------------
// grid (NSP/32, NB), block 512. g -> PB cm; theta(log2e), phi -> token-major.
__global__ __launch_bounds__(512) void proj_kernel(
    const float* __restrict__ x, const float* __restrict__ wT4,
    const float* __restrict__ g_b, const float* __restrict__ t_b,
    const float* __restrict__ p_b,
    u16* __restrict__ PB, u16* __restrict__ th_tm, u16* __restrict__ ph_tm)
{
    __shared__ float Xs[CC][36];
    __shared__ u16 Ot[192][40];

    const int b    = blockIdx.y;
    const int n0   = blockIdx.x * 32;
    const int tid  = threadIdx.x;
    const int lane = tid & 63;
    const int wv   = tid >> 6;
    const int t0   = wv * 4;

    const float* xb = x + (size_t)b * CC * NSP + n0;
    #pragma unroll
    for (int k = 0; k < 2; ++k) {
        int idx = tid + (k << 9);
        int c = idx >> 3, t4 = (idx & 7) << 2;
        *(f32x4*)&Xs[c][t4] = *(const f32x4*)(xb + (size_t)c * NSP + t4);
    }
    __syncthreads();

    float acc[3][4];
    {
        float b0 = g_b[lane], b1 = t_b[lane] * LOG2E, b2 = p_b[lane];
        #pragma unroll
        for (int t = 0; t < 4; ++t) { acc[0][t] = b0; acc[1][t] = b1; acc[2][t] = b2; }
    }

    const float* wp = wT4 + (lane << 2);
    #pragma unroll 8
    for (int c = 0; c < CC; ++c) {
        f32x4 wv4 = *(const f32x4*)(wp + (c << 8));
        f32x4 xv  = *(const f32x4*)&Xs[c][t0];
        #pragma unroll
        for (int t = 0; t < 4; ++t) {
            acc[0][t] += wv4[0] * xv[t];
            acc[1][t] += wv4[1] * xv[t];
            acc[2][t] += wv4[2] * xv[t];
        }
    }

    #pragma unroll
    for (int p = 0; p < 3; ++p) {
        #pragma unroll
        for (int i = 0; i < 2; ++i) {
            unsigned pk = (unsigned)f2bf(acc[p][2 * i]) | ((unsigned)f2bf(acc[p][2 * i + 1]) << 16);
            *(unsigned*)&Ot[lane + 64 * p][t0 + 2 * i] = pk;
        }
    }
    __syncthreads();

    // g (rows 0..63) -> PB channel-major
    if (tid < 256) {
        int row = tid >> 2, ch = tid & 3;
        uint4 v = *(const uint4*)&Ot[row][ch * 8];
        *(uint4*)(PB + (size_t)b * CIC * NSP + (size_t)row * NSP + n0 + ch * 8) = v;
    }
    // theta (rows 64..127), phi (128..191) -> token-major
    {
        int tok = tid >> 4, sel = (tid >> 3) & 1, c8 = (tid & 7) * 8;
        u16* dst = (sel ? ph_tm : th_tm) + ((size_t)b * NSP + n0 + tok) * 64 + c8;
        union { u16 t[8]; uint4 v4; } u;
        #pragma unroll
        for (int j = 0; j < 8; ++j) u.t[j] = Ot[64 + sel * 64 + c8 + j][tok];
        *(uint4*)dst = u.v4;
    }
}

// -------------------- Kernel 2: MFMA attention, swapped QK^T (R10-proven) -------
// grid (NSP/128, 2 kv-splits, NB), block 512 = 8 waves: q-strip s=w&3 (32 rows),
// kv sub-half h=w>>2 (1024 tokens, 16 iters of 64). S^T = mfma(K,Q) 32x32x16.
// Shift-softmax p=exp2(QK-32); per-lane pack + shfl_xor(32) -> PV A-frags in regs.
// Pipeline: write_t(next) + load_t(t+2) issued BEFORE compute so the barrier's
// vmcnt drain finds the loads already complete.
__global__ __launch_bounds__(512, 2) void attn_kernel(
    const u16* __restrict__ PB, const u16* __restrict__ th_tm,
    const u16* __restrict__ ph_tm,
    float* __restrict__ O_part, float* __restrict__ l_part)
{
    const int b    = blockIdx.z;
    const int kvs  = blockIdx.y;
    const int q0   = blockIdx.x << 7;
    const int tid  = threadIdx.x;
    const int lane = tid & 63;
    const int w    = tid >> 6;
    const int s    = w & 3;
    const int h    = w >> 2;
    const int l31  = lane & 31;
    const int l5   = lane >> 5;

    __shared__ __align__(16) char KV[2][2][2][8192];  // [dbuf][K/V][half][64 x 128B swz]

    const u16* gp = PB + (size_t)b * CIC * NSP;         // g cm [64][NSP]
    const u16* th = th_tm + (size_t)b * NSP * 64;       // theta tm
    const u16* ph = ph_tm + (size_t)b * NSP * 64;       // phi tm

    const int kb0 = kvs << 11;                          // 2048-token range

    const int srow = tid >> 3;
    const int scol = tid & 7;
    const int ldst = srow * 128 + (((scol ^ (srow & 7)) & 7) << 4);

    float4 rK0, rK1, rV0, rV1;
    auto load_t = [&](int t) {
        const int m0 = kb0 + (t << 6);
        rK0 = *(const float4*)(ph + ((size_t)(m0 + srow) << 6) + (scol << 3));
        rK1 = *(const float4*)(ph + ((size_t)(m0 + 1024 + srow) << 6) + (scol << 3));
        rV0 = *(const float4*)(gp + (size_t)srow * NSP + m0 + (scol << 3));
        rV1 = *(const float4*)(gp + (size_t)srow * NSP + m0 + 1024 + (scol << 3));
    };
    auto write_t = [&](int buf) {
        *(float4*)(&KV[buf][0][0][0] + ldst) = rK0;
        *(float4*)(&KV[buf][0][1][0] + ldst) = rK1;
        *(float4*)(&KV[buf][1][0][0] + ldst) = rV0;
        *(float4*)(&KV[buf][1][1][0] + ldst) = rV1;
    };

    // Q B-fragments (once): 4 x b128 from theta token-major
    s8bf qb[4];
    const int qtok = q0 + (s << 5) + l31;
    #pragma unroll
    for (int fc = 0; fc < 4; ++fc)
        qb[fc] = *(const s8bf*)(th + ((size_t)qtok << 6) + fc * 16 + l5 * 8);

    f32x16 Ov0, Ov1, cinit;
    #pragma unroll
    for (int i = 0; i < 16; ++i) { Ov0[i] = 0.f; Ov1[i] = 0.f; cinit[i] = -32.f; }
    float lr = 0.f;

    load_t(0); write_t(0); load_t(1);
    __syncthreads();

    u32 pk[2][4][2];

    for (int t = 0; t < 16; ++t) {
        const int buf = t & 1;

        // ---- stage next tile FIRST (write regs from t-1's load; issue t+2) ----
        if (t < 15) write_t(buf ^ 1);
        if (t < 14) load_t(t + 2);

        const char* Kb = &KV[buf][0][h][0];
        const char* Vb = &KV[buf][1][h][0];

        // ---- QK^T per kv 32-tile: S^T[kv][q], C-init = -32 (shift softmax) ----
        #pragma unroll
        for (int kt = 0; kt < 2; ++kt) {
            const int trow = l31 + (kt << 5);
            const int rswz = trow & 7;
            f32x16 sv = cinit;
            __builtin_amdgcn_s_setprio(1);
            #pragma unroll
            for (int fc = 0; fc < 4; ++fc) {
                s8bf ka = *(const s8bf*)(Kb + trow * 128 + (((2 * fc + l5) ^ rswz) << 4));
                sv = MFMA32(ka, qb[fc], sv);
            }
            __builtin_amdgcn_s_setprio(0);
            float e[16];
            #pragma unroll
            for (int i = 0; i < 16; ++i) e[i] = __builtin_amdgcn_exp2f(sv[i]);
            #pragma unroll
            for (int i = 0; i < 16; ++i) lr += e[i];
            #pragma unroll
            for (int m = 0; m < 4; ++m) {
                #pragma unroll
                for (int i = 0; i < 2; ++i) {
                    __hip_bfloat162 hh = __float22bfloat162_rn(
                        make_float2(e[4 * m + 2 * i], e[4 * m + 2 * i + 1]));
                    union { __hip_bfloat162 h2; u32 u; } cv; cv.h2 = hh;
                    pk[kt][m][i] = cv.u;
                }
            }
        }

        // ---- PV: assemble P A-frags in regs (shfl_xor 32), V B-frags from LDS ----
        __builtin_amdgcn_s_setprio(1);
        #pragma unroll
        for (int f = 0; f < 4; ++f) {
            const int tt = f >> 1;
            const int m0c = 2 * (f & 1);
            u32 sA0 = pk[tt][m0c][0],     sA1 = pk[tt][m0c][1];
            u32 sB0 = pk[tt][m0c + 1][0], sB1 = pk[tt][m0c + 1][1];
            u32 self0 = l5 ? sB0 : sA0, self1 = l5 ? sB1 : sA1;
            u32 send0 = l5 ? sA0 : sB0, send1 = l5 ? sA1 : sB1;
            u32 x0 = (u32)__shfl_xor((int)send0, 32);
            u32 x1 = (u32)__shfl_xor((int)send1, 32);
            union { u32 u[4]; s8bf v; } pa;
            pa.u[0] = l5 ? x0 : self0;
            pa.u[1] = l5 ? x1 : self1;
            pa.u[2] = l5 ? self0 : x0;
            pa.u[3] = l5 ? self1 : x1;
            const int c1 = l31 + 32;
            s8bf v0 = *(const s8bf*)(Vb + l31 * 128 + (((2 * f + l5) ^ (l31 & 7)) << 4));
            s8bf v1 = *(const s8bf*)(Vb + c1 * 128 + (((2 * f + l5) ^ (c1 & 7)) << 4));
            Ov0 = MFMA32(pa.v, v0, Ov0);
            Ov1 = MFMA32(pa.v, v1, Ov1);
        }
        __builtin_amdgcn_s_setprio(0);

        __syncthreads();
    }

    // ---- merge the 2 sub-halves via LDS (aliased over KV), write partials ----
    float lrh = lr + __shfl_xor(lr, 32);
    float* Olds = (float*)&KV[0][0][0][0];   // [4][32][64] = 32KB
    float* Llds = (float*)&KV[1][0][0][0];   // [4][32]

    if (h == 1) {
        #pragma unroll
        for (int reg = 0; reg < 16; ++reg) {
            int q = (reg & 3) + 8 * (reg >> 2) + 4 * l5;
            Olds[((s << 5) + q) * 64 + l31]      = Ov0[reg];
            Olds[((s << 5) + q) * 64 + 32 + l31] = Ov1[reg];
        }
        if (l5 == 0) Llds[(s << 5) + l31] = lrh;
    }
    __syncthreads();
    if (h == 0) {
        float ltot = lrh + Llds[(s << 5) + l31];
        float* Ob = O_part + ((size_t)b * 2 + kvs) * NSP * 64;
        #pragma unroll
        for (int reg = 0; reg < 16; ++reg) {
            int q = (reg & 3) + 8 * (reg >> 2) + 4 * l5;
            int qg = q0 + (s << 5) + q;
            Ob[(size_t)qg * 64 + l31]      = Ov0[reg] + Olds[((s << 5) + q) * 64 + l31];
            Ob[(size_t)qg * 64 + 32 + l31] = Ov1[reg] + Olds[((s << 5) + q) * 64 + 32 + l31];
        }
        if (l5 == 0)
            l_part[((size_t)b * 2 + kvs) * NSP + q0 + (s << 5) + l31] = ltot;
    }
}

// -------------------- Kernel 3: combine partials + W conv + fused stats ---------
// grid (NSP/32, NB), block 256. Stages y = (sum O_part)/(sum l) into LDS, GEMM,
// then per-channel sum/sumsq from the finished Of tile -> atomicAdd into parts.
__global__ __launch_bounds__(256) void wconv_kernel(
    const float* __restrict__ O_part, const float* __restrict__ l_part,
    const float* __restrict__ wT2p, const float* __restrict__ w_b,
    float* __restrict__ out, float* __restrict__ parts)
{
    __shared__ float Ys[CIC][36];
    __shared__ float Of[CC][36];

    const int b    = blockIdx.y;
    const int n0   = blockIdx.x * 32;
    const int tid  = threadIdx.x;
    const int lane = tid & 63;
    const int wv   = tid >> 6;
    const int t0   = wv * 8;

    // combine 2 kv-split partials, divide by l, transpose into Ys[ci][tok]
    #pragma unroll
    for (int rnd = 0; rnd < 2; ++rnd) {
        int tok = (tid >> 4) + (rnd << 4);
        int ci4 = tid & 15;
        int qg  = n0 + tok;
        f32x4 a = {0.f, 0.f, 0.f, 0.f};
        float ls = 0.f;
        #pragma unroll
        for (int kvs = 0; kvs < 2; ++kvs) {
            a += *(const f32x4*)(O_part + (((size_t)b * 2 + kvs) * NSP + qg) * 64 + (ci4 << 2));
            ls += l_part[((size_t)b * 2 + kvs) * NSP + qg];
        }
        float inv = 1.0f / ls;
        #pragma unroll
        for (int j = 0; j < 4; ++j) Ys[(ci4 << 2) + j][tok] = a[j] * inv;
    }
    __syncthreads();

    float acc[2][8];
    #pragma unroll
    for (int t = 0; t < 8; ++t) { acc[0][t] = 0.f; acc[1][t] = 0.f; }

    const float* wp = wT2p + (lane << 1);
    #pragma unroll 8
    for (int ci = 0; ci < CIC; ++ci) {
        f32x2 wv2 = *(const f32x2*)(wp + (ci << 7));
        f32x4 y0 = *(const f32x4*)&Ys[ci][t0];
        f32x4 y1 = *(const f32x4*)&Ys[ci][t0 + 4];
        #pragma unroll
        for (int t = 0; t < 4; ++t) {
            acc[0][t]     += wv2[0] * y0[t];
            acc[0][4 + t] += wv2[0] * y1[t];
            acc[1][t]     += wv2[1] * y0[t];
            acc[1][4 + t] += wv2[1] * y1[t];
        }
    }

    float b0 = w_b[lane], b1 = w_b[64 + lane];
    #pragma unroll
    for (int t = 0; t < 4; ++t) {
        Of[lane][t0 + t]          = acc[0][t] + b0;
        Of[lane][t0 + 4 + t]      = acc[0][4 + t] + b0;
        Of[64 + lane][t0 + t]     = acc[1][t] + b1;
        Of[64 + lane][t0 + 4 + t] = acc[1][4 + t] + b1;
    }
    __syncthreads();

    float* ob = out + (size_t)b * CC * NSP + n0;
    #pragma unroll
    for (int k = 0; k < 4; ++k) {
        int idx = tid + (k << 8);
        int row = idx >> 3, ch = idx & 7;
        *(float4*)(ob + (size_t)row * NSP + ch * 4) = *(const float4*)&Of[row][ch * 4];
    }

    // fused BN stats: threads 0..127 -> channel sum/sumsq over this 32-token tile
    if (tid < CC) {
        float s = 0.f, ss = 0.f;
        #pragma unroll
        for (int t2 = 0; t2 < 32; ++t2) {
            float v = Of[tid][t2];
            s += v; ss += v * v;
        }
        atomicAdd(&parts[tid], s);
        atomicAdd(&parts[CC + tid], ss);
    }
}

// -------------------- Kernel 4: BN finalize + residual (in-place) ---------------
__global__ __launch_bounds__(256) void bn_kernel(
    const float* __restrict__ x, const float* __restrict__ parts,
    const float* __restrict__ gamma, const float* __restrict__ beta,
    float* __restrict__ out)
{
    const int i = blockIdx.x * 256 + threadIdx.x;
    const int c = (i >> 10) & (CC - 1);
    float mean = parts[c] * (1.0f / 16384.0f);
    float var  = parts[CC + c] * (1.0f / 16384.0f) - mean * mean;
    float istd = rsqrtf(var + 1e-5f);
    float ga = gamma[c] * istd;
    float be = beta[c] - mean * ga;
    float4 wy = ((const float4*)out)[i];
    float4 xv = ((const float4*)x)[i];
    float4 o;
    o.x = wy.x * ga + be + xv.x;
    o.y = wy.y * ga + be + xv.y;
    o.z = wy.z * ga + be + xv.z;
    o.w = wy.w * ga + be + xv.w;
    ((float4*)out)[i] = o;
}

extern "C" void kernel_launch(void* const* d_in, const int* in_sizes, int n_in,
                              void* d_out, int out_size, void* d_ws, size_t ws_size,
                              hipStream_t stream)
{
    const float* x    = (const float*)d_in[0];
    const float* g_w  = (const float*)d_in[1];
    const float* g_b  = (const float*)d_in[2];
    const float* t_w  = (const float*)d_in[3];
    const float* t_b  = (const float*)d_in[4];
    const float* p_w  = (const float*)d_in[5];
    const float* p_b  = (const float*)d_in[6];
    const float* w_w  = (const float*)d_in[7];
    const float* w_b  = (const float*)d_in[8];
    const float* bn_g = (const float*)d_in[9];
    const float* bn_b = (const float*)d_in[10];
    float* out = (float*)d_out;
    char* ws8  = (char*)d_ws;

    u16*   PB    = (u16*)(ws8 + WSB_PB);
    u16*   TH    = (u16*)(ws8 + WSB_TH);
    u16*   PH    = (u16*)(ws8 + WSB_PH);
    float* OP    = (float*)(ws8 + WSB_OP);
    float* LP    = (float*)(ws8 + WSB_LP);
    float* wT4   = (float*)(ws8 + WSB_WT4);
    float* wT2p  = (float*)(ws8 + WSB_WT2P);
    float* parts = (float*)(ws8 + WSB_PARTS);

    prep_kernel <<<dim3(CC), 256, 0, stream>>>(g_w, t_w, p_w, w_w, wT4, wT2p, parts);
    proj_kernel <<<dim3(NSP / 32, NB), 512, 0, stream>>>(x, wT4, g_b, t_b, p_b, PB, TH, PH);
    attn_kernel <<<dim3(NSP / 128, 2, NB), 512, 0, stream>>>(PB, TH, PH, OP, LP);
    wconv_kernel<<<dim3(NSP / 32, NB), 256, 0, stream>>>(OP, LP, wT2p, w_b, out, parts);
    bn_kernel   <<<dim3(2048), 256, 0, stream>>>(x, parts, bn_g, bn_b, out);
}

// Round 13
// 78.979 us; speedup vs baseline: 1.0402x; 1.0402x over previous
//
#include <hip/hip_runtime.h>
#include <hip/hip_bf16.h>
#include <math.h>

#define NSP 4096   // H*W
#define CC  128    // channels
#define CIC 64     // inter channels
#define NB  4      // batch
#define LOG2E 1.4426950408889634f

typedef unsigned short u16;
typedef unsigned int u32;
typedef short s8bf __attribute__((ext_vector_type(8)));
typedef float f32x4 __attribute__((ext_vector_type(4)));
typedef float f32x2 __attribute__((ext_vector_type(2)));
typedef float f32x16 __attribute__((ext_vector_type(16)));

#define MFMA32(a, b, c) __builtin_amdgcn_mfma_f32_32x32x16_bf16(a, b, c, 0, 0, 0)

// workspace byte offsets
#define WSB_PB    0                              // bf16 [B][64][NSP] g channel-major
#define WSB_TH    (NB * CIC * NSP * 2)           // bf16 [B][NSP][64] theta*log2e token-major
#define WSB_PH    (WSB_TH + NB * NSP * CIC * 2)  // bf16 [B][NSP][64] phi token-major
#define WSB_OP    (WSB_PH + NB * NSP * CIC * 2)  // f32 [B][2][NSP][64] O partials (8MB)
#define WSB_LP    (WSB_OP + (size_t)NB * 2 * NSP * CIC * 4)  // f32 [B][2][NSP]
#define WSB_WT4   (WSB_LP + NB * 2 * NSP * 4)    // f32 [128][64][4] proj weights
#define WSB_WT2P  (WSB_WT4 + CC * 256 * 4)       // f32 [64][64][2] wconv weight pairs
#define WSB_PARTS (WSB_WT2P + CIC * CC * 4)      // f32 [128][4][2] stats partials

__device__ __forceinline__ u16 f2bf(float f) {
    union { float f; unsigned u; } v; v.f = f;
    unsigned r = v.u + 0x7fffu + ((v.u >> 16) & 1u);
    return (u16)(r >> 16);
}

// -------------------- Kernel 0: weight repack prep ------------------------------
__global__ __launch_bounds__(256) void prep_kernel(
    const float* __restrict__ g_w, const float* __restrict__ t_w,
    const float* __restrict__ p_w, const float* __restrict__ w_w,
    float* __restrict__ wT4, float* __restrict__ wT2p)
{
    const int c = blockIdx.x;
    const int o = threadIdx.x;
    if (o < 192) {
        float v;
        if (o < 64)       v = g_w[o * CC + c];
        else if (o < 128) v = t_w[(o - 64) * CC + c] * LOG2E;
        else              v = p_w[(o - 128) * CC + c];
        wT4[(c << 8) + ((o & 63) << 2) + (o >> 6)] = v;
    } else {
        wT4[(c << 8) + ((o - 192) << 2) + 3] = 0.f;
    }
    if (o < CIC)
        wT2p[(o << 7) + ((c & 63) << 1) + (c >> 6)] = w_w[c * CIC + o];
}

// -------------------- Kernel 1: fused 1x1 projections ---------------------------
// grid (NSP/32, NB), block 512. g -> PB cm; theta(log2e), phi -> token-major.
__global__ __launch_bounds__(512) void proj_kernel(
    const float* __restrict__ x, const float* __restrict__ wT4,
    const float* __restrict__ g_b, const float* __restrict__ t_b,
    const float* __restrict__ p_b,
    u16* __restrict__ PB, u16* __restrict__ th_tm, u16* __restrict__ ph_tm)
{
    __shared__ float Xs[CC][36];
    __shared__ u16 Ot[192][40];

    const int b    = blockIdx.y;
    const int n0   = blockIdx.x * 32;
    const int tid  = threadIdx.x;
    const int lane = tid & 63;
    const int wv   = tid >> 6;
    const int t0   = wv * 4;

    const float* xb = x + (size_t)b * CC * NSP + n0;
    #pragma unroll
    for (int k = 0; k < 2; ++k) {
        int idx = tid + (k << 9);
        int c = idx >> 3, t4 = (idx & 7) << 2;
        *(f32x4*)&Xs[c][t4] = *(const f32x4*)(xb + (size_t)c * NSP + t4);
    }
    __syncthreads();

    float acc[3][4];
    {
        float b0 = g_b[lane], b1 = t_b[lane] * LOG2E, b2 = p_b[lane];
        #pragma unroll
        for (int t = 0; t < 4; ++t) { acc[0][t] = b0; acc[1][t] = b1; acc[2][t] = b2; }
    }

    const float* wp = wT4 + (lane << 2);
    #pragma unroll 8
    for (int c = 0; c < CC; ++c) {
        f32x4 wv4 = *(const f32x4*)(wp + (c << 8));
        f32x4 xv  = *(const f32x4*)&Xs[c][t0];
        #pragma unroll
        for (int t = 0; t < 4; ++t) {
            acc[0][t] += wv4[0] * xv[t];
            acc[1][t] += wv4[1] * xv[t];
            acc[2][t] += wv4[2] * xv[t];
        }
    }

    #pragma unroll
    for (int p = 0; p < 3; ++p) {
        #pragma unroll
        for (int i = 0; i < 2; ++i) {
            unsigned pk = (unsigned)f2bf(acc[p][2 * i]) | ((unsigned)f2bf(acc[p][2 * i + 1]) << 16);
            *(unsigned*)&Ot[lane + 64 * p][t0 + 2 * i] = pk;
        }
    }
    __syncthreads();

    // g (rows 0..63) -> PB channel-major
    if (tid < 256) {
        int row = tid >> 2, ch = tid & 3;
        uint4 v = *(const uint4*)&Ot[row][ch * 8];
        *(uint4*)(PB + (size_t)b * CIC * NSP + (size_t)row * NSP + n0 + ch * 8) = v;
    }
    // theta (rows 64..127), phi (128..191) -> token-major
    {
        int tok = tid >> 4, sel = (tid >> 3) & 1, c8 = (tid & 7) * 8;
        u16* dst = (sel ? ph_tm : th_tm) + ((size_t)b * NSP + n0 + tok) * 64 + c8;
        union { u16 t[8]; uint4 v4; } u;
        #pragma unroll
        for (int j = 0; j < 8; ++j) u.t[j] = Ot[64 + sel * 64 + c8 + j][tok];
        *(uint4*)dst = u.v4;
    }
}

// -------------------- Kernel 2: MFMA attention, swapped QK^T --------------------
// grid (NSP/128, 2 kv-splits, NB), block 512 = 8 waves: q-strip s=w&3 (32 rows),
// kv sub-half h=w>>2 (1024 tokens, 16 iters of 64). S^T = mfma(K,Q) 32x32x16.
// Shift-softmax p=exp2(QK-32); per-lane pack + shfl_xor(32) -> PV A-frags in regs.
// launch_bounds(512,4): cap VGPR at 128 (est. usage ~110) -> 2 blocks/CU,
// 4 waves/SIMD for dependency-stall hiding (attn is stall-bound, not issue-bound).
__global__ __launch_bounds__(512, 4) void attn_kernel(
    const u16* __restrict__ PB, const u16* __restrict__ th_tm,
    const u16* __restrict__ ph_tm,
    float* __restrict__ O_part, float* __restrict__ l_part)
{
    const int b    = blockIdx.z;
    const int kvs  = blockIdx.y;
    const int q0   = blockIdx.x << 7;
    const int tid  = threadIdx.x;
    const int lane = tid & 63;
    const int w    = tid >> 6;
    const int s    = w & 3;
    const int h    = w >> 2;
    const int l31  = lane & 31;
    const int l5   = lane >> 5;

    __shared__ __align__(16) char KV[2][2][2][8192];  // [dbuf][K/V][half][64 x 128B swz]

    const u16* gp = PB + (size_t)b * CIC * NSP;         // g cm [64][NSP]
    const u16* th = th_tm + (size_t)b * NSP * 64;       // theta tm
    const u16* ph = ph_tm + (size_t)b * NSP * 64;       // phi tm

    const int kb0 = kvs << 11;                          // 2048-token range

    const int srow = tid >> 3;
    const int scol = tid & 7;
    const int ldst = srow * 128 + (((scol ^ (srow & 7)) & 7) << 4);

    float4 rK0, rK1, rV0, rV1;
    auto load_t = [&](int t) {
        const int m0 = kb0 + (t << 6);
        rK0 = *(const float4*)(ph + ((size_t)(m0 + srow) << 6) + (scol << 3));
        rK1 = *(const float4*)(ph + ((size_t)(m0 + 1024 + srow) << 6) + (scol << 3));
        rV0 = *(const float4*)(gp + (size_t)srow * NSP + m0 + (scol << 3));
        rV1 = *(const float4*)(gp + (size_t)srow * NSP + m0 + 1024 + (scol << 3));
    };
    auto write_t = [&](int buf) {
        *(float4*)(&KV[buf][0][0][0] + ldst) = rK0;
        *(float4*)(&KV[buf][0][1][0] + ldst) = rK1;
        *(float4*)(&KV[buf][1][0][0] + ldst) = rV0;
        *(float4*)(&KV[buf][1][1][0] + ldst) = rV1;
    };

    // Q B-fragments (once): 4 x b128 from theta token-major
    s8bf qb[4];
    const int qtok = q0 + (s << 5) + l31;
    #pragma unroll
    for (int fc = 0; fc < 4; ++fc)
        qb[fc] = *(const s8bf*)(th + ((size_t)qtok << 6) + fc * 16 + l5 * 8);

    f32x16 Ov0, Ov1, cinit;
    #pragma unroll
    for (int i = 0; i < 16; ++i) { Ov0[i] = 0.f; Ov1[i] = 0.f; cinit[i] = -32.f; }
    float lr = 0.f;

    load_t(0); write_t(0); load_t(1);
    __syncthreads();

    u32 pk[2][4][2];

    for (int t = 0; t < 16; ++t) {
        const int buf = t & 1;

        // ---- stage next tile FIRST (write regs from t-1's load; issue t+2) ----
        if (t < 15) write_t(buf ^ 1);
        if (t < 14) load_t(t + 2);

        const char* Kb = &KV[buf][0][h][0];
        const char* Vb = &KV[buf][1][h][0];

        // ---- QK^T per kv 32-tile: S^T[kv][q], C-init = -32 (shift softmax) ----
        #pragma unroll
        for (int kt = 0; kt < 2; ++kt) {
            const int trow = l31 + (kt << 5);
            const int rswz = trow & 7;
            f32x16 sv = cinit;
            __builtin_amdgcn_s_setprio(1);
            #pragma unroll
            for (int fc = 0; fc < 4; ++fc) {
                s8bf ka = *(const s8bf*)(Kb + trow * 128 + (((2 * fc + l5) ^ rswz) << 4));
                sv = MFMA32(ka, qb[fc], sv);
            }
            __builtin_amdgcn_s_setprio(0);
            float e[16];
            #pragma unroll
            for (int i = 0; i < 16; ++i) e[i] = __builtin_amdgcn_exp2f(sv[i]);
            #pragma unroll
            for (int i = 0; i < 16; ++i) lr += e[i];
            #pragma unroll
            for (int m = 0; m < 4; ++m) {
                #pragma unroll
                for (int i = 0; i < 2; ++i) {
                    __hip_bfloat162 hh = __float22bfloat162_rn(
                        make_float2(e[4 * m + 2 * i], e[4 * m + 2 * i + 1]));
                    union { __hip_bfloat162 h2; u32 u; } cv; cv.h2 = hh;
                    pk[kt][m][i] = cv.u;
                }
            }
        }

        // ---- PV: assemble P A-frags in regs (shfl_xor 32), V B-frags from LDS ----
        __builtin_amdgcn_s_setprio(1);
        #pragma unroll
        for (int f = 0; f < 4; ++f) {
            const int tt = f >> 1;
            const int m0c = 2 * (f & 1);
            u32 sA0 = pk[tt][m0c][0],     sA1 = pk[tt][m0c][1];
            u32 sB0 = pk[tt][m0c + 1][0], sB1 = pk[tt][m0c + 1][1];
            u32 self0 = l5 ? sB0 : sA0, self1 = l5 ? sB1 : sA1;
            u32 send0 = l5 ? sA0 : sB0, send1 = l5 ? sA1 : sB1;
            u32 x0 = (u32)__shfl_xor((int)send0, 32);
            u32 x1 = (u32)__shfl_xor((int)send1, 32);
            union { u32 u[4]; s8bf v; } pa;
            pa.u[0] = l5 ? x0 : self0;
            pa.u[1] = l5 ? x1 : self1;
            pa.u[2] = l5 ? self0 : x0;
            pa.u[3] = l5 ? self1 : x1;
            const int c1 = l31 + 32;
            s8bf v0 = *(const s8bf*)(Vb + l31 * 128 + (((2 * f + l5) ^ (l31 & 7)) << 4));
            s8bf v1 = *(const s8bf*)(Vb + c1 * 128 + (((2 * f + l5) ^ (c1 & 7)) << 4));
            Ov0 = MFMA32(pa.v, v0, Ov0);
            Ov1 = MFMA32(pa.v, v1, Ov1);
        }
        __builtin_amdgcn_s_setprio(0);

        __syncthreads();
    }

    // ---- merge the 2 sub-halves via LDS (aliased over KV), write partials ----
    float lrh = lr + __shfl_xor(lr, 32);
    float* Olds = (float*)&KV[0][0][0][0];   // [4][32][64] = 32KB
    float* Llds = (float*)&KV[1][0][0][0];   // [4][32]

    if (h == 1) {
        #pragma unroll
        for (int reg = 0; reg < 16; ++reg) {
            int q = (reg & 3) + 8 * (reg >> 2) + 4 * l5;
            Olds[((s << 5) + q) * 64 + l31]      = Ov0[reg];
            Olds[((s << 5) + q) * 64 + 32 + l31] = Ov1[reg];
        }
        if (l5 == 0) Llds[(s << 5) + l31] = lrh;
    }
    __syncthreads();
    if (h == 0) {
        float ltot = lrh + Llds[(s << 5) + l31];
        float* Ob = O_part + ((size_t)b * 2 + kvs) * NSP * 64;
        #pragma unroll
        for (int reg = 0; reg < 16; ++reg) {
            int q = (reg & 3) + 8 * (reg >> 2) + 4 * l5;
            int qg = q0 + (s << 5) + q;
            Ob[(size_t)qg * 64 + l31]      = Ov0[reg] + Olds[((s << 5) + q) * 64 + l31];
            Ob[(size_t)qg * 64 + 32 + l31] = Ov1[reg] + Olds[((s << 5) + q) * 64 + 32 + l31];
        }
        if (l5 == 0)
            l_part[((size_t)b * 2 + kvs) * NSP + q0 + (s << 5) + l31] = ltot;
    }
}

// -------------------- Kernel 3: combine partials + W conv -> d_out --------------
// grid (NSP/32, NB), block 256. Stages y = (sum O_part)/(sum l) into LDS, then GEMM.
__global__ __launch_bounds__(256) void wconv_kernel(
    const float* __restrict__ O_part, const float* __restrict__ l_part,
    const float* __restrict__ wT2p, const float* __restrict__ w_b,
    float* __restrict__ out)
{
    __shared__ float Ys[CIC][36];
    __shared__ float Of[CC][36];

    const int b    = blockIdx.y;
    const int n0   = blockIdx.x * 32;
    const int tid  = threadIdx.x;
    const int lane = tid & 63;
    const int wv   = tid >> 6;
    const int t0   = wv * 8;

    // combine 2 kv-split partials, divide by l, transpose into Ys[ci][tok]
    #pragma unroll
    for (int rnd = 0; rnd < 2; ++rnd) {
        int tok = (tid >> 4) + (rnd << 4);
        int ci4 = tid & 15;
        int qg  = n0 + tok;
        f32x4 a = {0.f, 0.f, 0.f, 0.f};
        float ls = 0.f;
        #pragma unroll
        for (int kvs = 0; kvs < 2; ++kvs) {
            a += *(const f32x4*)(O_part + (((size_t)b * 2 + kvs) * NSP + qg) * 64 + (ci4 << 2));
            ls += l_part[((size_t)b * 2 + kvs) * NSP + qg];
        }
        float inv = 1.0f / ls;
        #pragma unroll
        for (int j = 0; j < 4; ++j) Ys[(ci4 << 2) + j][tok] = a[j] * inv;
    }
    __syncthreads();

    float acc[2][8];
    #pragma unroll
    for (int t = 0; t < 8; ++t) { acc[0][t] = 0.f; acc[1][t] = 0.f; }

    const float* wp = wT2p + (lane << 1);
    #pragma unroll 8
    for (int ci = 0; ci < CIC; ++ci) {
        f32x2 wv2 = *(const f32x2*)(wp + (ci << 7));
        f32x4 y0 = *(const f32x4*)&Ys[ci][t0];
        f32x4 y1 = *(const f32x4*)&Ys[ci][t0 + 4];
        #pragma unroll
        for (int t = 0; t < 4; ++t) {
            acc[0][t]     += wv2[0] * y0[t];
            acc[0][4 + t] += wv2[0] * y1[t];
            acc[1][t]     += wv2[1] * y0[t];
            acc[1][4 + t] += wv2[1] * y1[t];
        }
    }

    float b0 = w_b[lane], b1 = w_b[64 + lane];
    #pragma unroll
    for (int t = 0; t < 4; ++t) {
        Of[lane][t0 + t]          = acc[0][t] + b0;
        Of[lane][t0 + 4 + t]      = acc[0][4 + t] + b0;
        Of[64 + lane][t0 + t]     = acc[1][t] + b1;
        Of[64 + lane][t0 + 4 + t] = acc[1][4 + t] + b1;
    }
    __syncthreads();

    float* ob = out + (size_t)b * CC * NSP + n0;
    #pragma unroll
    for (int k = 0; k < 4; ++k) {
        int idx = tid + (k << 8);
        int row = idx >> 3, ch = idx & 7;
        *(float4*)(ob + (size_t)row * NSP + ch * 4) = *(const float4*)&Of[row][ch * 4];
    }
}

// -------------------- Kernel 4: per-channel partial stats -----------------------
__global__ __launch_bounds__(256) void stats_kernel(
    const float* __restrict__ wy, float* __restrict__ parts)
{
    const int c   = blockIdx.x >> 2;
    const int qd  = blockIdx.x & 3;
    const int tid = threadIdx.x;
    float s = 0.f, ss = 0.f;
    #pragma unroll 4
    for (int k = 0; k < 16; ++k) {
        int i = qd * 4096 + k * 256 + tid;
        int b = i >> 12, n = i & (NSP - 1);
        float v = wy[((size_t)b * CC + c) * NSP + n];
        s += v; ss += v * v;
    }
    #pragma unroll
    for (int off = 32; off > 0; off >>= 1) {
        s  += __shfl_down(s, off, 64);
        ss += __shfl_down(ss, off, 64);
    }
    __shared__ float sred[4], ssred[4];
    const int wid = tid >> 6, lane = tid & 63;
    if (lane == 0) { sred[wid] = s; ssred[wid] = ss; }
    __syncthreads();
    if (tid == 0) {
        parts[(c * 4 + qd) * 2]     = sred[0] + sred[1] + sred[2] + sred[3];
        parts[(c * 4 + qd) * 2 + 1] = ssred[0] + ssred[1] + ssred[2] + ssred[3];
    }
}

// -------------------- Kernel 5: BN finalize + residual (in-place) ---------------
__global__ __launch_bounds__(256) void bn_kernel(
    const float* __restrict__ x, const float* __restrict__ parts,
    const float* __restrict__ gamma, const float* __restrict__ beta,
    float* __restrict__ out)
{
    const int i = blockIdx.x * 256 + threadIdx.x;
    const int c = (i >> 10) & (CC - 1);
    float s  = parts[c * 8]     + parts[c * 8 + 2] + parts[c * 8 + 4] + parts[c * 8 + 6];
    float ss = parts[c * 8 + 1] + parts[c * 8 + 3] + parts[c * 8 + 5] + parts[c * 8 + 7];
    float mean = s * (1.0f / 16384.0f);
    float var  = ss * (1.0f / 16384.0f) - mean * mean;
    float istd = rsqrtf(var + 1e-5f);
    float ga = gamma[c] * istd;
    float be = beta[c] - mean * ga;
    float4 wy = ((const float4*)out)[i];
    float4 xv = ((const float4*)x)[i];
    float4 o;
    o.x = wy.x * ga + be + xv.x;
    o.y = wy.y * ga + be + xv.y;
    o.z = wy.z * ga + be + xv.z;
    o.w = wy.w * ga + be + xv.w;
    ((float4*)out)[i] = o;
}

extern "C" void kernel_launch(void* const* d_in, const int* in_sizes, int n_in,
                              void* d_out, int out_size, void* d_ws, size_t ws_size,
                              hipStream_t stream)
{
    const float* x    = (const float*)d_in[0];
    const float* g_w  = (const float*)d_in[1];
    const float* g_b  = (const float*)d_in[2];
    const float* t_w  = (const float*)d_in[3];
    const float* t_b  = (const float*)d_in[4];
    const float* p_w  = (const float*)d_in[5];
    const float* p_b  = (const float*)d_in[6];
    const float* w_w  = (const float*)d_in[7];
    const float* w_b  = (const float*)d_in[8];
    const float* bn_g = (const float*)d_in[9];
    const float* bn_b = (const float*)d_in[10];
    float* out = (float*)d_out;
    char* ws8  = (char*)d_ws;

    u16*   PB    = (u16*)(ws8 + WSB_PB);
    u16*   TH    = (u16*)(ws8 + WSB_TH);
    u16*   PH    = (u16*)(ws8 + WSB_PH);
    float* OP    = (float*)(ws8 + WSB_OP);
    float* LP    = (float*)(ws8 + WSB_LP);
    float* wT4   = (float*)(ws8 + WSB_WT4);
    float* wT2p  = (float*)(ws8 + WSB_WT2P);
    float* parts = (float*)(ws8 + WSB_PARTS);

    prep_kernel <<<dim3(CC), 256, 0, stream>>>(g_w, t_w, p_w, w_w, wT4, wT2p);
    proj_kernel <<<dim3(NSP / 32, NB), 512, 0, stream>>>(x, wT4, g_b, t_b, p_b, PB, TH, PH);
    attn_kernel <<<dim3(NSP / 128, 2, NB), 512, 0, stream>>>(PB, TH, PH, OP, LP);
    wconv_kernel<<<dim3(NSP / 32, NB), 256, 0, stream>>>(OP, LP, wT2p, w_b, out);
    stats_kernel<<<dim3(CC * 4), 256, 0, stream>>>(out, parts);
    bn_kernel   <<<dim3(2048), 256, 0, stream>>>(x, parts, bn_g, bn_b, out);
}

// Round 14
// 72.468 us; speedup vs baseline: 1.1336x; 1.0899x over previous
//
#include <hip/hip_runtime.h>
#include <hip/hip_bf16.h>
#include <math.h>

#define NSP 4096   // H*W
#define CC  128    // channels
#define CIC 64     // inter channels
#define NB  4      // batch
#define LOG2E 1.4426950408889634f

typedef unsigned short u16;
typedef unsigned int u32;
typedef short s8bf __attribute__((ext_vector_type(8)));
typedef float f32x4 __attribute__((ext_vector_type(4)));
typedef float f32x2 __attribute__((ext_vector_type(2)));
typedef float f32x16 __attribute__((ext_vector_type(16)));

#define MFMA32(a, b, c) __builtin_amdgcn_mfma_f32_32x32x16_bf16(a, b, c, 0, 0, 0)

// workspace byte offsets
#define WSB_PB    0                              // bf16 [B][64][NSP] g channel-major
#define WSB_TH    (NB * CIC * NSP * 2)           // bf16 [B][NSP][64] theta*log2e token-major
#define WSB_PH    (WSB_TH + NB * NSP * CIC * 2)  // bf16 [B][NSP][64] phi token-major
#define WSB_OP    (WSB_PH + NB * NSP * CIC * 2)  // f32 [B][2][NSP][64] O partials (8MB)
#define WSB_LP    (WSB_OP + (size_t)NB * 2 * NSP * CIC * 4)  // f32 [B][2][NSP]
#define WSB_WT4   (WSB_LP + NB * 2 * NSP * 4)    // f32 [128][64][4] proj weights
#define WSB_WT2P  (WSB_WT4 + CC * 256 * 4)       // f32 [64][64][2] wconv weight pairs
#define WSB_PARTS (WSB_WT2P + CIC * CC * 4)      // f32 [128][4][2] stats partials

__device__ __forceinline__ u16 f2bf(float f) {
    union { float f; unsigned u; } v; v.f = f;
    unsigned r = v.u + 0x7fffu + ((v.u >> 16) & 1u);
    return (u16)(r >> 16);
}

// -------------------- Kernel 0: weight repack prep ------------------------------
__global__ __launch_bounds__(256) void prep_kernel(
    const float* __restrict__ g_w, const float* __restrict__ t_w,
    const float* __restrict__ p_w, const float* __restrict__ w_w,
    float* __restrict__ wT4, float* __restrict__ wT2p)
{
    const int c = blockIdx.x;
    const int o = threadIdx.x;
    if (o < 192) {
        float v;
        if (o < 64)       v = g_w[o * CC + c];
        else if (o < 128) v = t_w[(o - 64) * CC + c] * LOG2E;
        else              v = p_w[(o - 128) * CC + c];
        wT4[(c << 8) + ((o & 63) << 2) + (o >> 6)] = v;
    } else {
        wT4[(c << 8) + ((o - 192) << 2) + 3] = 0.f;
    }
    if (o < CIC)
        wT2p[(o << 7) + ((c & 63) << 1) + (c >> 6)] = w_w[c * CIC + o];
}

// -------------------- Kernel 1: fused 1x1 projections (64-token tile) -----------
// grid (NSP/64, NB), block 512 = 8 waves; wave -> 8 tokens, lane -> 3 out-chans.
// 64 tokens/block halves the per-block-redundant weight L2 stream vs 32-token
// tile (each wave privately streams 128KB of wT4; fewer blocks = less traffic).
__global__ __launch_bounds__(512) void proj_kernel(
    const float* __restrict__ x, const float* __restrict__ wT4,
    const float* __restrict__ g_b, const float* __restrict__ t_b,
    const float* __restrict__ p_b,
    u16* __restrict__ PB, u16* __restrict__ th_tm, u16* __restrict__ ph_tm)
{
    __shared__ float Xs[CC][68];   // 34.8 KB
    __shared__ u16 Ot[192][72];    // 27.6 KB

    const int b    = blockIdx.y;
    const int n0   = blockIdx.x * 64;
    const int tid  = threadIdx.x;
    const int lane = tid & 63;
    const int wv   = tid >> 6;
    const int t0   = wv * 8;

    // stage x tile [128 ch][64 tok]
    const float* xb = x + (size_t)b * CC * NSP + n0;
    #pragma unroll
    for (int k = 0; k < 4; ++k) {
        int idx = tid + (k << 9);          // 0..2047
        int c = idx >> 4, t4 = (idx & 15) << 2;
        *(f32x4*)&Xs[c][t4] = *(const f32x4*)(xb + (size_t)c * NSP + t4);
    }
    __syncthreads();

    float acc[3][8];
    {
        float b0 = g_b[lane], b1 = t_b[lane] * LOG2E, b2 = p_b[lane];
        #pragma unroll
        for (int t = 0; t < 8; ++t) { acc[0][t] = b0; acc[1][t] = b1; acc[2][t] = b2; }
    }

    const float* wp = wT4 + (lane << 2);
    #pragma unroll 4
    for (int c = 0; c < CC; ++c) {
        f32x4 wv4 = *(const f32x4*)(wp + (c << 8));
        f32x4 xv0 = *(const f32x4*)&Xs[c][t0];
        f32x4 xv1 = *(const f32x4*)&Xs[c][t0 + 4];
        #pragma unroll
        for (int t = 0; t < 4; ++t) {
            acc[0][t]     += wv4[0] * xv0[t];
            acc[0][4 + t] += wv4[0] * xv1[t];
            acc[1][t]     += wv4[1] * xv0[t];
            acc[1][4 + t] += wv4[1] * xv1[t];
            acc[2][t]     += wv4[2] * xv0[t];
            acc[2][4 + t] += wv4[2] * xv1[t];
        }
    }

    // pack pairs -> u32 LDS stores
    #pragma unroll
    for (int p = 0; p < 3; ++p) {
        #pragma unroll
        for (int i = 0; i < 4; ++i) {
            unsigned pk = (unsigned)f2bf(acc[p][2 * i]) | ((unsigned)f2bf(acc[p][2 * i + 1]) << 16);
            *(unsigned*)&Ot[lane + 64 * p][t0 + 2 * i] = pk;
        }
    }
    __syncthreads();

    // g (rows 0..63) -> PB channel-major: 64 rows x 8 chunks of 16B
    {
        int row = tid >> 3, ch = tid & 7;
        uint4 v = *(const uint4*)&Ot[row][ch * 8];
        *(uint4*)(PB + (size_t)b * CIC * NSP + (size_t)row * NSP + n0 + ch * 8) = v;
    }
    // theta (rows 64..127), phi (128..191) -> token-major: 64 tok x 2 sel x 8 chunks
    #pragma unroll
    for (int k = 0; k < 2; ++k) {
        int idx = tid + (k << 9);          // 0..1023
        int tok = idx >> 4, sel = (idx >> 3) & 1, c8 = (idx & 7) * 8;
        u16* dst = (sel ? ph_tm : th_tm) + ((size_t)b * NSP + n0 + tok) * 64 + c8;
        union { u16 t[8]; uint4 v4; } u;
        #pragma unroll
        for (int j = 0; j < 8; ++j) u.t[j] = Ot[64 + sel * 64 + c8 + j][tok];
        *(uint4*)dst = u.v4;
    }
}

// -------------------- Kernel 2: MFMA attention, swapped QK^T (R10-proven) -------
// grid (NSP/128, 2 kv-splits, NB), block 512 = 8 waves: q-strip s=w&3 (32 rows),
// kv sub-half h=w>>2 (1024 tokens, 16 iters of 64). S^T = mfma(K,Q) 32x32x16.
// Shift-softmax p=exp2(QK-32); per-lane pack + shfl_xor(32) -> PV A-frags in regs.
// Pipeline: write_t(next) + load_t(t+2) issued BEFORE compute.
__global__ __launch_bounds__(512, 2) void attn_kernel(
    const u16* __restrict__ PB, const u16* __restrict__ th_tm,
    const u16* __restrict__ ph_tm,
    float* __restrict__ O_part, float* __restrict__ l_part)
{
    const int b    = blockIdx.z;
    const int kvs  = blockIdx.y;
    const int q0   = blockIdx.x << 7;
    const int tid  = threadIdx.x;
    const int lane = tid & 63;
    const int w    = tid >> 6;
    const int s    = w & 3;
    const int h    = w >> 2;
    const int l31  = lane & 31;
    const int l5   = lane >> 5;

    __shared__ __align__(16) char KV[2][2][2][8192];  // [dbuf][K/V][half][64 x 128B swz]

    const u16* gp = PB + (size_t)b * CIC * NSP;         // g cm [64][NSP]
    const u16* th = th_tm + (size_t)b * NSP * 64;       // theta tm
    const u16* ph = ph_tm + (size_t)b * NSP * 64;       // phi tm

    const int kb0 = kvs << 11;                          // 2048-token range

    const int srow = tid >> 3;
    const int scol = tid & 7;
    const int ldst = srow * 128 + (((scol ^ (srow & 7)) & 7) << 4);

    float4 rK0, rK1, rV0, rV1;
    auto load_t = [&](int t) {
        const int m0 = kb0 + (t << 6);
        rK0 = *(const float4*)(ph + ((size_t)(m0 + srow) << 6) + (scol << 3));
        rK1 = *(const float4*)(ph + ((size_t)(m0 + 1024 + srow) << 6) + (scol << 3));
        rV0 = *(const float4*)(gp + (size_t)srow * NSP + m0 + (scol << 3));
        rV1 = *(const float4*)(gp + (size_t)srow * NSP + m0 + 1024 + (scol << 3));
    };
    auto write_t = [&](int buf) {
        *(float4*)(&KV[buf][0][0][0] + ldst) = rK0;
        *(float4*)(&KV[buf][0][1][0] + ldst) = rK1;
        *(float4*)(&KV[buf][1][0][0] + ldst) = rV0;
        *(float4*)(&KV[buf][1][1][0] + ldst) = rV1;
    };

    // Q B-fragments (once): 4 x b128 from theta token-major
    s8bf qb[4];
    const int qtok = q0 + (s << 5) + l31;
    #pragma unroll
    for (int fc = 0; fc < 4; ++fc)
        qb[fc] = *(const s8bf*)(th + ((size_t)qtok << 6) + fc * 16 + l5 * 8);

    f32x16 Ov0, Ov1, cinit;
    #pragma unroll
    for (int i = 0; i < 16; ++i) { Ov0[i] = 0.f; Ov1[i] = 0.f; cinit[i] = -32.f; }
    float lr = 0.f;

    load_t(0); write_t(0); load_t(1);
    __syncthreads();

    u32 pk[2][4][2];

    for (int t = 0; t < 16; ++t) {
        const int buf = t & 1;

        // ---- stage next tile FIRST (write regs from t-1's load; issue t+2) ----
        if (t < 15) write_t(buf ^ 1);
        if (t < 14) load_t(t + 2);

        const char* Kb = &KV[buf][0][h][0];
        const char* Vb = &KV[buf][1][h][0];

        // ---- QK^T per kv 32-tile: S^T[kv][q], C-init = -32 (shift softmax) ----
        #pragma unroll
        for (int kt = 0; kt < 2; ++kt) {
            const int trow = l31 + (kt << 5);
            const int rswz = trow & 7;
            f32x16 sv = cinit;
            __builtin_amdgcn_s_setprio(1);
            #pragma unroll
            for (int fc = 0; fc < 4; ++fc) {
                s8bf ka = *(const s8bf*)(Kb + trow * 128 + (((2 * fc + l5) ^ rswz) << 4));
                sv = MFMA32(ka, qb[fc], sv);
            }
            __builtin_amdgcn_s_setprio(0);
            float e[16];
            #pragma unroll
            for (int i = 0; i < 16; ++i) e[i] = __builtin_amdgcn_exp2f(sv[i]);
            #pragma unroll
            for (int i = 0; i < 16; ++i) lr += e[i];
            #pragma unroll
            for (int m = 0; m < 4; ++m) {
                #pragma unroll
                for (int i = 0; i < 2; ++i) {
                    __hip_bfloat162 hh = __float22bfloat162_rn(
                        make_float2(e[4 * m + 2 * i], e[4 * m + 2 * i + 1]));
                    union { __hip_bfloat162 h2; u32 u; } cv; cv.h2 = hh;
                    pk[kt][m][i] = cv.u;
                }
            }
        }

        // ---- PV: assemble P A-frags in regs (shfl_xor 32), V B-frags from LDS ----
        __builtin_amdgcn_s_setprio(1);
        #pragma unroll
        for (int f = 0; f < 4; ++f) {
            const int tt = f >> 1;
            const int m0c = 2 * (f & 1);
            u32 sA0 = pk[tt][m0c][0],     sA1 = pk[tt][m0c][1];
            u32 sB0 = pk[tt][m0c + 1][0], sB1 = pk[tt][m0c + 1][1];
            u32 self0 = l5 ? sB0 : sA0, self1 = l5 ? sB1 : sA1;
            u32 send0 = l5 ? sA0 : sB0, send1 = l5 ? sA1 : sB1;
            u32 x0 = (u32)__shfl_xor((int)send0, 32);
            u32 x1 = (u32)__shfl_xor((int)send1, 32);
            union { u32 u[4]; s8bf v; } pa;
            pa.u[0] = l5 ? x0 : self0;
            pa.u[1] = l5 ? x1 : self1;
            pa.u[2] = l5 ? self0 : x0;
            pa.u[3] = l5 ? self1 : x1;
            const int c1 = l31 + 32;
            s8bf v0 = *(const s8bf*)(Vb + l31 * 128 + (((2 * f + l5) ^ (l31 & 7)) << 4));
            s8bf v1 = *(const s8bf*)(Vb + c1 * 128 + (((2 * f + l5) ^ (c1 & 7)) << 4));
            Ov0 = MFMA32(pa.v, v0, Ov0);
            Ov1 = MFMA32(pa.v, v1, Ov1);
        }
        __builtin_amdgcn_s_setprio(0);

        __syncthreads();
    }

    // ---- merge the 2 sub-halves via LDS (aliased over KV), write partials ----
    float lrh = lr + __shfl_xor(lr, 32);
    float* Olds = (float*)&KV[0][0][0][0];   // [4][32][64] = 32KB
    float* Llds = (float*)&KV[1][0][0][0];   // [4][32]

    if (h == 1) {
        #pragma unroll
        for (int reg = 0; reg < 16; ++reg) {
            int q = (reg & 3) + 8 * (reg >> 2) + 4 * l5;
            Olds[((s << 5) + q) * 64 + l31]      = Ov0[reg];
            Olds[((s << 5) + q) * 64 + 32 + l31] = Ov1[reg];
        }
        if (l5 == 0) Llds[(s << 5) + l31] = lrh;
    }
    __syncthreads();
    if (h == 0) {
        float ltot = lrh + Llds[(s << 5) + l31];
        float* Ob = O_part + ((size_t)b * 2 + kvs) * NSP * 64;
        #pragma unroll
        for (int reg = 0; reg < 16; ++reg) {
            int q = (reg & 3) + 8 * (reg >> 2) + 4 * l5;
            int qg = q0 + (s << 5) + q;
            Ob[(size_t)qg * 64 + l31]      = Ov0[reg] + Olds[((s << 5) + q) * 64 + l31];
            Ob[(size_t)qg * 64 + 32 + l31] = Ov1[reg] + Olds[((s << 5) + q) * 64 + 32 + l31];
        }
        if (l5 == 0)
            l_part[((size_t)b * 2 + kvs) * NSP + q0 + (s << 5) + l31] = ltot;
    }
}

// -------------------- Kernel 3: combine partials + W conv -> d_out --------------
// grid (NSP/32, NB), block 256. Stages y = (sum O_part)/(sum l) into LDS, then GEMM.
__global__ __launch_bounds__(256) void wconv_kernel(
    const float* __restrict__ O_part, const float* __restrict__ l_part,
    const float* __restrict__ wT2p, const float* __restrict__ w_b,
    float* __restrict__ out)
{
    __shared__ float Ys[CIC][36];
    __shared__ float Of[CC][36];

    const int b    = blockIdx.y;
    const int n0   = blockIdx.x * 32;
    const int tid  = threadIdx.x;
    const int lane = tid & 63;
    const int wv   = tid >> 6;
    const int t0   = wv * 8;

    // combine 2 kv-split partials, divide by l, transpose into Ys[ci][tok]
    #pragma unroll
    for (int rnd = 0; rnd < 2; ++rnd) {
        int tok = (tid >> 4) + (rnd << 4);
        int ci4 = tid & 15;
        int qg  = n0 + tok;
        f32x4 a = {0.f, 0.f, 0.f, 0.f};
        float ls = 0.f;
        #pragma unroll
        for (int kvs = 0; kvs < 2; ++kvs) {
            a += *(const f32x4*)(O_part + (((size_t)b * 2 + kvs) * NSP + qg) * 64 + (ci4 << 2));
            ls += l_part[((size_t)b * 2 + kvs) * NSP + qg];
        }
        float inv = 1.0f / ls;
        #pragma unroll
        for (int j = 0; j < 4; ++j) Ys[(ci4 << 2) + j][tok] = a[j] * inv;
    }
    __syncthreads();

    float acc[2][8];
    #pragma unroll
    for (int t = 0; t < 8; ++t) { acc[0][t] = 0.f; acc[1][t] = 0.f; }

    const float* wp = wT2p + (lane << 1);
    #pragma unroll 8
    for (int ci = 0; ci < CIC; ++ci) {
        f32x2 wv2 = *(const f32x2*)(wp + (ci << 7));
        f32x4 y0 = *(const f32x4*)&Ys[ci][t0];
        f32x4 y1 = *(const f32x4*)&Ys[ci][t0 + 4];
        #pragma unroll
        for (int t = 0; t < 4; ++t) {
            acc[0][t]     += wv2[0] * y0[t];
            acc[0][4 + t] += wv2[0] * y1[t];
            acc[1][t]     += wv2[1] * y0[t];
            acc[1][4 + t] += wv2[1] * y1[t];
        }
    }

    float b0 = w_b[lane], b1 = w_b[64 + lane];
    #pragma unroll
    for (int t = 0; t < 4; ++t) {
        Of[lane][t0 + t]          = acc[0][t] + b0;
        Of[lane][t0 + 4 + t]      = acc[0][4 + t] + b0;
        Of[64 + lane][t0 + t]     = acc[1][t] + b1;
        Of[64 + lane][t0 + 4 + t] = acc[1][4 + t] + b1;
    }
    __syncthreads();

    float* ob = out + (size_t)b * CC * NSP + n0;
    #pragma unroll
    for (int k = 0; k < 4; ++k) {
        int idx = tid + (k << 8);
        int row = idx >> 3, ch = idx & 7;
        *(float4*)(ob + (size_t)row * NSP + ch * 4) = *(const float4*)&Of[row][ch * 4];
    }
}

// -------------------- Kernel 4: per-channel partial stats -----------------------
__global__ __launch_bounds__(256) void stats_kernel(
    const float* __restrict__ wy, float* __restrict__ parts)
{
    const int c   = blockIdx.x >> 2;
    const int qd  = blockIdx.x & 3;
    const int tid = threadIdx.x;
    float s = 0.f, ss = 0.f;
    #pragma unroll 4
    for (int k = 0; k < 16; ++k) {
        int i = qd * 4096 + k * 256 + tid;
        int b = i >> 12, n = i & (NSP - 1);
        float v = wy[((size_t)b * CC + c) * NSP + n];
        s += v; ss += v * v;
    }
    #pragma unroll
    for (int off = 32; off > 0; off >>= 1) {
        s  += __shfl_down(s, off, 64);
        ss += __shfl_down(ss, off, 64);
    }
    __shared__ float sred[4], ssred[4];
    const int wid = tid >> 6, lane = tid & 63;
    if (lane == 0) { sred[wid] = s; ssred[wid] = ss; }
    __syncthreads();
    if (tid == 0) {
        parts[(c * 4 + qd) * 2]     = sred[0] + sred[1] + sred[2] + sred[3];
        parts[(c * 4 + qd) * 2 + 1] = ssred[0] + ssred[1] + ssred[2] + ssred[3];
    }
}

// -------------------- Kernel 5: BN finalize + residual (in-place) ---------------
__global__ __launch_bounds__(256) void bn_kernel(
    const float* __restrict__ x, const float* __restrict__ parts,
    const float* __restrict__ gamma, const float* __restrict__ beta,
    float* __restrict__ out)
{
    const int i = blockIdx.x * 256 + threadIdx.x;
    const int c = (i >> 10) & (CC - 1);
    float s  = parts[c * 8]     + parts[c * 8 + 2] + parts[c * 8 + 4] + parts[c * 8 + 6];
    float ss = parts[c * 8 + 1] + parts[c * 8 + 3] + parts[c * 8 + 5] + parts[c * 8 + 7];
    float mean = s * (1.0f / 16384.0f);
    float var  = ss * (1.0f / 16384.0f) - mean * mean;
    float istd = rsqrtf(var + 1e-5f);
    float ga = gamma[c] * istd;
    float be = beta[c] - mean * ga;
    float4 wy = ((const float4*)out)[i];
    float4 xv = ((const float4*)x)[i];
    float4 o;
    o.x = wy.x * ga + be + xv.x;
    o.y = wy.y * ga + be + xv.y;
    o.z = wy.z * ga + be + xv.z;
    o.w = wy.w * ga + be + xv.w;
    ((float4*)out)[i] = o;
}

extern "C" void kernel_launch(void* const* d_in, const int* in_sizes, int n_in,
                              void* d_out, int out_size, void* d_ws, size_t ws_size,
                              hipStream_t stream)
{
    const float* x    = (const float*)d_in[0];
    const float* g_w  = (const float*)d_in[1];
    const float* g_b  = (const float*)d_in[2];
    const float* t_w  = (const float*)d_in[3];
    const float* t_b  = (const float*)d_in[4];
    const float* p_w  = (const float*)d_in[5];
    const float* p_b  = (const float*)d_in[6];
    const float* w_w  = (const float*)d_in[7];
    const float* w_b  = (const float*)d_in[8];
    const float* bn_g = (const float*)d_in[9];
    const float* bn_b = (const float*)d_in[10];
    float* out = (float*)d_out;
    char* ws8  = (char*)d_ws;

    u16*   PB    = (u16*)(ws8 + WSB_PB);
    u16*   TH    = (u16*)(ws8 + WSB_TH);
    u16*   PH    = (u16*)(ws8 + WSB_PH);
    float* OP    = (float*)(ws8 + WSB_OP);
    float* LP    = (float*)(ws8 + WSB_LP);
    float* wT4   = (float*)(ws8 + WSB_WT4);
    float* wT2p  = (float*)(ws8 + WSB_WT2P);
    float* parts = (float*)(ws8 + WSB_PARTS);

    prep_kernel <<<dim3(CC), 256, 0, stream>>>(g_w, t_w, p_w, w_w, wT4, wT2p);
    proj_kernel <<<dim3(NSP / 64, NB), 512, 0, stream>>>(x, wT4, g_b, t_b, p_b, PB, TH, PH);
    attn_kernel <<<dim3(NSP / 128, 2, NB), 512, 0, stream>>>(PB, TH, PH, OP, LP);
    wconv_kernel<<<dim3(NSP / 32, NB), 256, 0, stream>>>(OP, LP, wT2p, w_b, out);
    stats_kernel<<<dim3(CC * 4), 256, 0, stream>>>(out, parts);
    bn_kernel   <<<dim3(2048), 256, 0, stream>>>(x, parts, bn_g, bn_b, out);
}

// Round 15
// 69.190 us; speedup vs baseline: 1.1873x; 1.0474x over previous
//
#include <hip/hip_runtime.h>
#include <hip/hip_bf16.h>
#include <math.h>

#define NSP 4096   // H*W
#define CC  128    // channels
#define CIC 64     // inter channels
#define NB  4      // batch
#define LOG2E 1.4426950408889634f

typedef unsigned short u16;
typedef unsigned int u32;
typedef short s8bf __attribute__((ext_vector_type(8)));
typedef float f32x4 __attribute__((ext_vector_type(4)));
typedef float f32x2 __attribute__((ext_vector_type(2)));
typedef float f32x16 __attribute__((ext_vector_type(16)));

#define MFMA32(a, b, c) __builtin_amdgcn_mfma_f32_32x32x16_bf16(a, b, c, 0, 0, 0)

// workspace byte offsets
#define WSB_PB    0                              // bf16 [B][64][NSP] g channel-major
#define WSB_TH    (NB * CIC * NSP * 2)           // bf16 [B][NSP][64] theta*log2e token-major
#define WSB_PH    (WSB_TH + NB * NSP * CIC * 2)  // bf16 [B][NSP][64] phi token-major
#define WSB_OP    (WSB_PH + NB * NSP * CIC * 2)  // f32 [B][2][NSP][64] O partials (8MB)
#define WSB_LP    (WSB_OP + (size_t)NB * 2 * NSP * CIC * 4)  // f32 [B][2][NSP]
#define WSB_WT4   (WSB_LP + NB * 2 * NSP * 4)    // f32 [128][64][4] proj weights
#define WSB_WT2P  (WSB_WT4 + CC * 256 * 4)       // f32 [64][64][2] wconv weight pairs
#define WSB_P2    (WSB_WT2P + CIC * CC * 4)      // f32 [128 c][2][512 blk] stats partials

__device__ __forceinline__ u16 f2bf(float f) {
    union { float f; unsigned u; } v; v.f = f;
    unsigned r = v.u + 0x7fffu + ((v.u >> 16) & 1u);
    return (u16)(r >> 16);
}

// -------------------- Kernel 0: weight repack prep ------------------------------
__global__ __launch_bounds__(256) void prep_kernel(
    const float* __restrict__ g_w, const float* __restrict__ t_w,
    const float* __restrict__ p_w, const float* __restrict__ w_w,
    float* __restrict__ wT4, float* __restrict__ wT2p)
{
    const int c = blockIdx.x;
    const int o = threadIdx.x;
    if (o < 192) {
        float v;
        if (o < 64)       v = g_w[o * CC + c];
        else if (o < 128) v = t_w[(o - 64) * CC + c] * LOG2E;
        else              v = p_w[(o - 128) * CC + c];
        wT4[(c << 8) + ((o & 63) << 2) + (o >> 6)] = v;
    } else {
        wT4[(c << 8) + ((o - 192) << 2) + 3] = 0.f;
    }
    if (o < CIC)
        wT2p[(o << 7) + ((c & 63) << 1) + (c >> 6)] = w_w[c * CIC + o];
}

// -------------------- Kernel 1: fused 1x1 projections (64-token tile) -----------
// grid (NSP/64, NB), block 512 = 8 waves; wave -> 8 tokens, lane -> 3 out-chans.
__global__ __launch_bounds__(512) void proj_kernel(
    const float* __restrict__ x, const float* __restrict__ wT4,
    const float* __restrict__ g_b, const float* __restrict__ t_b,
    const float* __restrict__ p_b,
    u16* __restrict__ PB, u16* __restrict__ th_tm, u16* __restrict__ ph_tm)
{
    __shared__ float Xs[CC][68];   // 34.8 KB
    __shared__ u16 Ot[192][72];    // 27.6 KB

    const int b    = blockIdx.y;
    const int n0   = blockIdx.x * 64;
    const int tid  = threadIdx.x;
    const int lane = tid & 63;
    const int wv   = tid >> 6;
    const int t0   = wv * 8;

    // stage x tile [128 ch][64 tok]
    const float* xb = x + (size_t)b * CC * NSP + n0;
    #pragma unroll
    for (int k = 0; k < 4; ++k) {
        int idx = tid + (k << 9);          // 0..2047
        int c = idx >> 4, t4 = (idx & 15) << 2;
        *(f32x4*)&Xs[c][t4] = *(const f32x4*)(xb + (size_t)c * NSP + t4);
    }
    __syncthreads();

    float acc[3][8];
    {
        float b0 = g_b[lane], b1 = t_b[lane] * LOG2E, b2 = p_b[lane];
        #pragma unroll
        for (int t = 0; t < 8; ++t) { acc[0][t] = b0; acc[1][t] = b1; acc[2][t] = b2; }
    }

    const float* wp = wT4 + (lane << 2);
    #pragma unroll 4
    for (int c = 0; c < CC; ++c) {
        f32x4 wv4 = *(const f32x4*)(wp + (c << 8));
        f32x4 xv0 = *(const f32x4*)&Xs[c][t0];
        f32x4 xv1 = *(const f32x4*)&Xs[c][t0 + 4];
        #pragma unroll
        for (int t = 0; t < 4; ++t) {
            acc[0][t]     += wv4[0] * xv0[t];
            acc[0][4 + t] += wv4[0] * xv1[t];
            acc[1][t]     += wv4[1] * xv0[t];
            acc[1][4 + t] += wv4[1] * xv1[t];
            acc[2][t]     += wv4[2] * xv0[t];
            acc[2][4 + t] += wv4[2] * xv1[t];
        }
    }

    // pack pairs -> u32 LDS stores
    #pragma unroll
    for (int p = 0; p < 3; ++p) {
        #pragma unroll
        for (int i = 0; i < 4; ++i) {
            unsigned pk = (unsigned)f2bf(acc[p][2 * i]) | ((unsigned)f2bf(acc[p][2 * i + 1]) << 16);
            *(unsigned*)&Ot[lane + 64 * p][t0 + 2 * i] = pk;
        }
    }
    __syncthreads();

    // g (rows 0..63) -> PB channel-major: 64 rows x 8 chunks of 16B
    {
        int row = tid >> 3, ch = tid & 7;
        uint4 v = *(const uint4*)&Ot[row][ch * 8];
        *(uint4*)(PB + (size_t)b * CIC * NSP + (size_t)row * NSP + n0 + ch * 8) = v;
    }
    // theta (rows 64..127), phi (128..191) -> token-major
    #pragma unroll
    for (int k = 0; k < 2; ++k) {
        int idx = tid + (k << 9);          // 0..1023
        int tok = idx >> 4, sel = (idx >> 3) & 1, c8 = (idx & 7) * 8;
        u16* dst = (sel ? ph_tm : th_tm) + ((size_t)b * NSP + n0 + tok) * 64 + c8;
        union { u16 t[8]; uint4 v4; } u;
        #pragma unroll
        for (int j = 0; j < 8; ++j) u.t[j] = Ot[64 + sel * 64 + c8 + j][tok];
        *(uint4*)dst = u.v4;
    }
}

// -------------------- Kernel 2: MFMA attention, swapped QK^T (R10-proven) -------
// grid (NSP/128, 2 kv-splits, NB), block 512 = 8 waves: q-strip s=w&3 (32 rows),
// kv sub-half h=w>>2 (1024 tokens, 16 iters of 64). S^T = mfma(K,Q) 32x32x16.
// Shift-softmax p=exp2(QK-32); per-lane pack + shfl_xor(32) -> PV A-frags in regs.
__global__ __launch_bounds__(512, 2) void attn_kernel(
    const u16* __restrict__ PB, const u16* __restrict__ th_tm,
    const u16* __restrict__ ph_tm,
    float* __restrict__ O_part, float* __restrict__ l_part)
{
    const int b    = blockIdx.z;
    const int kvs  = blockIdx.y;
    const int q0   = blockIdx.x << 7;
    const int tid  = threadIdx.x;
    const int lane = tid & 63;
    const int w    = tid >> 6;
    const int s    = w & 3;
    const int h    = w >> 2;
    const int l31  = lane & 31;
    const int l5   = lane >> 5;

    __shared__ __align__(16) char KV[2][2][2][8192];  // [dbuf][K/V][half][64 x 128B swz]

    const u16* gp = PB + (size_t)b * CIC * NSP;         // g cm [64][NSP]
    const u16* th = th_tm + (size_t)b * NSP * 64;       // theta tm
    const u16* ph = ph_tm + (size_t)b * NSP * 64;       // phi tm

    const int kb0 = kvs << 11;                          // 2048-token range

    const int srow = tid >> 3;
    const int scol = tid & 7;
    const int ldst = srow * 128 + (((scol ^ (srow & 7)) & 7) << 4);

    float4 rK0, rK1, rV0, rV1;
    auto load_t = [&](int t) {
        const int m0 = kb0 + (t << 6);
        rK0 = *(const float4*)(ph + ((size_t)(m0 + srow) << 6) + (scol << 3));
        rK1 = *(const float4*)(ph + ((size_t)(m0 + 1024 + srow) << 6) + (scol << 3));
        rV0 = *(const float4*)(gp + (size_t)srow * NSP + m0 + (scol << 3));
        rV1 = *(const float4*)(gp + (size_t)srow * NSP + m0 + 1024 + (scol << 3));
    };
    auto write_t = [&](int buf) {
        *(float4*)(&KV[buf][0][0][0] + ldst) = rK0;
        *(float4*)(&KV[buf][0][1][0] + ldst) = rK1;
        *(float4*)(&KV[buf][1][0][0] + ldst) = rV0;
        *(float4*)(&KV[buf][1][1][0] + ldst) = rV1;
    };

    // Q B-fragments (once): 4 x b128 from theta token-major
    s8bf qb[4];
    const int qtok = q0 + (s << 5) + l31;
    #pragma unroll
    for (int fc = 0; fc < 4; ++fc)
        qb[fc] = *(const s8bf*)(th + ((size_t)qtok << 6) + fc * 16 + l5 * 8);

    f32x16 Ov0, Ov1, cinit;
    #pragma unroll
    for (int i = 0; i < 16; ++i) { Ov0[i] = 0.f; Ov1[i] = 0.f; cinit[i] = -32.f; }
    float lr = 0.f;

    load_t(0); write_t(0); load_t(1);
    __syncthreads();

    u32 pk[2][4][2];

    for (int t = 0; t < 16; ++t) {
        const int buf = t & 1;

        // ---- stage next tile FIRST (write regs from t-1's load; issue t+2) ----
        if (t < 15) write_t(buf ^ 1);
        if (t < 14) load_t(t + 2);

        const char* Kb = &KV[buf][0][h][0];
        const char* Vb = &KV[buf][1][h][0];

        // ---- QK^T per kv 32-tile: S^T[kv][q], C-init = -32 (shift softmax) ----
        #pragma unroll
        for (int kt = 0; kt < 2; ++kt) {
            const int trow = l31 + (kt << 5);
            const int rswz = trow & 7;
            f32x16 sv = cinit;
            __builtin_amdgcn_s_setprio(1);
            #pragma unroll
            for (int fc = 0; fc < 4; ++fc) {
                s8bf ka = *(const s8bf*)(Kb + trow * 128 + (((2 * fc + l5) ^ rswz) << 4));
                sv = MFMA32(ka, qb[fc], sv);
            }
            __builtin_amdgcn_s_setprio(0);
            float e[16];
            #pragma unroll
            for (int i = 0; i < 16; ++i) e[i] = __builtin_amdgcn_exp2f(sv[i]);
            #pragma unroll
            for (int i = 0; i < 16; ++i) lr += e[i];
            #pragma unroll
            for (int m = 0; m < 4; ++m) {
                #pragma unroll
                for (int i = 0; i < 2; ++i) {
                    __hip_bfloat162 hh = __float22bfloat162_rn(
                        make_float2(e[4 * m + 2 * i], e[4 * m + 2 * i + 1]));
                    union { __hip_bfloat162 h2; u32 u; } cv; cv.h2 = hh;
                    pk[kt][m][i] = cv.u;
                }
            }
        }

        // ---- PV: assemble P A-frags in regs (shfl_xor 32), V B-frags from LDS ----
        __builtin_amdgcn_s_setprio(1);
        #pragma unroll
        for (int f = 0; f < 4; ++f) {
            const int tt = f >> 1;
            const int m0c = 2 * (f & 1);
            u32 sA0 = pk[tt][m0c][0],     sA1 = pk[tt][m0c][1];
            u32 sB0 = pk[tt][m0c + 1][0], sB1 = pk[tt][m0c + 1][1];
            u32 self0 = l5 ? sB0 : sA0, self1 = l5 ? sB1 : sA1;
            u32 send0 = l5 ? sA0 : sB0, send1 = l5 ? sA1 : sB1;
            u32 x0 = (u32)__shfl_xor((int)send0, 32);
            u32 x1 = (u32)__shfl_xor((int)send1, 32);
            union { u32 u[4]; s8bf v; } pa;
            pa.u[0] = l5 ? x0 : self0;
            pa.u[1] = l5 ? x1 : self1;
            pa.u[2] = l5 ? self0 : x0;
            pa.u[3] = l5 ? self1 : x1;
            const int c1 = l31 + 32;
            s8bf v0 = *(const s8bf*)(Vb + l31 * 128 + (((2 * f + l5) ^ (l31 & 7)) << 4));
            s8bf v1 = *(const s8bf*)(Vb + c1 * 128 + (((2 * f + l5) ^ (c1 & 7)) << 4));
            Ov0 = MFMA32(pa.v, v0, Ov0);
            Ov1 = MFMA32(pa.v, v1, Ov1);
        }
        __builtin_amdgcn_s_setprio(0);

        __syncthreads();
    }

    // ---- merge the 2 sub-halves via LDS (aliased over KV), write partials ----
    float lrh = lr + __shfl_xor(lr, 32);
    float* Olds = (float*)&KV[0][0][0][0];   // [4][32][64] = 32KB
    float* Llds = (float*)&KV[1][0][0][0];   // [4][32]

    if (h == 1) {
        #pragma unroll
        for (int reg = 0; reg < 16; ++reg) {
            int q = (reg & 3) + 8 * (reg >> 2) + 4 * l5;
            Olds[((s << 5) + q) * 64 + l31]      = Ov0[reg];
            Olds[((s << 5) + q) * 64 + 32 + l31] = Ov1[reg];
        }
        if (l5 == 0) Llds[(s << 5) + l31] = lrh;
    }
    __syncthreads();
    if (h == 0) {
        float ltot = lrh + Llds[(s << 5) + l31];
        float* Ob = O_part + ((size_t)b * 2 + kvs) * NSP * 64;
        #pragma unroll
        for (int reg = 0; reg < 16; ++reg) {
            int q = (reg & 3) + 8 * (reg >> 2) + 4 * l5;
            int qg = q0 + (s << 5) + q;
            Ob[(size_t)qg * 64 + l31]      = Ov0[reg] + Olds[((s << 5) + q) * 64 + l31];
            Ob[(size_t)qg * 64 + 32 + l31] = Ov1[reg] + Olds[((s << 5) + q) * 64 + 32 + l31];
        }
        if (l5 == 0)
            l_part[((size_t)b * 2 + kvs) * NSP + q0 + (s << 5) + l31] = ltot;
    }
}

// -------------------- Kernel 3: combine + W conv + per-block BN partials --------
// grid (NSP/32, NB), block 256. After the GEMM epilogue, threads 0..127 write this
// block's per-channel sum/sumsq to DISTINCT slots parts2[c][{0,1}][blk] (no atomics).
__global__ __launch_bounds__(256) void wconv_kernel(
    const float* __restrict__ O_part, const float* __restrict__ l_part,
    const float* __restrict__ wT2p, const float* __restrict__ w_b,
    float* __restrict__ out, float* __restrict__ parts2)
{
    __shared__ float Ys[CIC][36];
    __shared__ float Of[CC][36];

    const int b    = blockIdx.y;
    const int n0   = blockIdx.x * 32;
    const int tid  = threadIdx.x;
    const int lane = tid & 63;
    const int wv   = tid >> 6;
    const int t0   = wv * 8;

    // combine 2 kv-split partials, divide by l, transpose into Ys[ci][tok]
    #pragma unroll
    for (int rnd = 0; rnd < 2; ++rnd) {
        int tok = (tid >> 4) + (rnd << 4);
        int ci4 = tid & 15;
        int qg  = n0 + tok;
        f32x4 a = {0.f, 0.f, 0.f, 0.f};
        float ls = 0.f;
        #pragma unroll
        for (int kvs = 0; kvs < 2; ++kvs) {
            a += *(const f32x4*)(O_part + (((size_t)b * 2 + kvs) * NSP + qg) * 64 + (ci4 << 2));
            ls += l_part[((size_t)b * 2 + kvs) * NSP + qg];
        }
        float inv = 1.0f / ls;
        #pragma unroll
        for (int j = 0; j < 4; ++j) Ys[(ci4 << 2) + j][tok] = a[j] * inv;
    }
    __syncthreads();

    float acc[2][8];
    #pragma unroll
    for (int t = 0; t < 8; ++t) { acc[0][t] = 0.f; acc[1][t] = 0.f; }

    const float* wp = wT2p + (lane << 1);
    #pragma unroll 8
    for (int ci = 0; ci < CIC; ++ci) {
        f32x2 wv2 = *(const f32x2*)(wp + (ci << 7));
        f32x4 y0 = *(const f32x4*)&Ys[ci][t0];
        f32x4 y1 = *(const f32x4*)&Ys[ci][t0 + 4];
        #pragma unroll
        for (int t = 0; t < 4; ++t) {
            acc[0][t]     += wv2[0] * y0[t];
            acc[0][4 + t] += wv2[0] * y1[t];
            acc[1][t]     += wv2[1] * y0[t];
            acc[1][4 + t] += wv2[1] * y1[t];
        }
    }

    float b0 = w_b[lane], b1 = w_b[64 + lane];
    #pragma unroll
    for (int t = 0; t < 4; ++t) {
        Of[lane][t0 + t]          = acc[0][t] + b0;
        Of[lane][t0 + 4 + t]      = acc[0][4 + t] + b0;
        Of[64 + lane][t0 + t]     = acc[1][t] + b1;
        Of[64 + lane][t0 + 4 + t] = acc[1][4 + t] + b1;
    }
    __syncthreads();

    float* ob = out + (size_t)b * CC * NSP + n0;
    #pragma unroll
    for (int k = 0; k < 4; ++k) {
        int idx = tid + (k << 8);
        int row = idx >> 3, ch = idx & 7;
        *(float4*)(ob + (size_t)row * NSP + ch * 4) = *(const float4*)&Of[row][ch * 4];
    }

    // per-block BN partials (distinct slots, no atomics): blk = b*128 + tileX
    if (tid < CC) {
        float s = 0.f, ss = 0.f;
        #pragma unroll 8
        for (int t2 = 0; t2 < 32; ++t2) {
            float v = Of[tid][t2];
            s += v; ss += v * v;
        }
        const int blk = b * (NSP / 32) + blockIdx.x;    // 0..511
        parts2[(size_t)tid * 1024 + blk]       = s;
        parts2[(size_t)tid * 1024 + 512 + blk] = ss;
    }
}

// -------------------- Kernel 4: BN finalize + residual (reduce + in-place) ------
// grid 2048, block 256. Each block covers exactly one channel c; reduces that
// channel's 512 partials (2KB contiguous, L2-resident) then applies BN+residual.
__global__ __launch_bounds__(256) void bn_kernel(
    const float* __restrict__ x, const float* __restrict__ parts2,
    const float* __restrict__ gamma, const float* __restrict__ beta,
    float* __restrict__ out)
{
    __shared__ float red[8];
    const int tid = threadIdx.x;
    const int i   = blockIdx.x * 256 + tid;         // float4 index
    const int c   = (i >> 10) & (CC - 1);           // constant per block

    // reduce 512 sums + 512 sumsqs
    const float* P = parts2 + (size_t)c * 1024;
    float s  = P[tid]       + P[256 + tid];         // tid<256 covers 0..511
    float ss = P[512 + tid] + P[768 + tid];
    #pragma unroll
    for (int off = 32; off > 0; off >>= 1) {
        s  += __shfl_down(s, off, 64);
        ss += __shfl_down(ss, off, 64);
    }
    const int wid = tid >> 6, lane = tid & 63;
    if (lane == 0) { red[wid] = s; red[4 + wid] = ss; }
    __syncthreads();
    float st  = red[0] + red[1] + red[2] + red[3];
    float sst = red[4] + red[5] + red[6] + red[7];

    float mean = st * (1.0f / 16384.0f);
    float var  = sst * (1.0f / 16384.0f) - mean * mean;
    float istd = rsqrtf(var + 1e-5f);
    float ga = gamma[c] * istd;
    float be = beta[c] - mean * ga;
    float4 wy = ((const float4*)out)[i];
    float4 xv = ((const float4*)x)[i];
    float4 o;
    o.x = wy.x * ga + be + xv.x;
    o.y = wy.y * ga + be + xv.y;
    o.z = wy.z * ga + be + xv.z;
    o.w = wy.w * ga + be + xv.w;
    ((float4*)out)[i] = o;
}

extern "C" void kernel_launch(void* const* d_in, const int* in_sizes, int n_in,
                              void* d_out, int out_size, void* d_ws, size_t ws_size,
                              hipStream_t stream)
{
    const float* x    = (const float*)d_in[0];
    const float* g_w  = (const float*)d_in[1];
    const float* g_b  = (const float*)d_in[2];
    const float* t_w  = (const float*)d_in[3];
    const float* t_b  = (const float*)d_in[4];
    const float* p_w  = (const float*)d_in[5];
    const float* p_b  = (const float*)d_in[6];
    const float* w_w  = (const float*)d_in[7];
    const float* w_b  = (const float*)d_in[8];
    const float* bn_g = (const float*)d_in[9];
    const float* bn_b = (const float*)d_in[10];
    float* out = (float*)d_out;
    char* ws8  = (char*)d_ws;

    u16*   PB     = (u16*)(ws8 + WSB_PB);
    u16*   TH     = (u16*)(ws8 + WSB_TH);
    u16*   PH     = (u16*)(ws8 + WSB_PH);
    float* OP     = (float*)(ws8 + WSB_OP);
    float* LP     = (float*)(ws8 + WSB_LP);
    float* wT4    = (float*)(ws8 + WSB_WT4);
    float* wT2p   = (float*)(ws8 + WSB_WT2P);
    float* parts2 = (float*)(ws8 + WSB_P2);

    prep_kernel <<<dim3(CC), 256, 0, stream>>>(g_w, t_w, p_w, w_w, wT4, wT2p);
    proj_kernel <<<dim3(NSP / 64, NB), 512, 0, stream>>>(x, wT4, g_b, t_b, p_b, PB, TH, PH);
    attn_kernel <<<dim3(NSP / 128, 2, NB), 512, 0, stream>>>(PB, TH, PH, OP, LP);
    wconv_kernel<<<dim3(NSP / 32, NB), 256, 0, stream>>>(OP, LP, wT2p, w_b, out, parts2);
    bn_kernel   <<<dim3(2048), 256, 0, stream>>>(x, parts2, bn_g, bn_b, out);
}